// Round 1
// baseline (121.768 us; speedup 1.0000x reference)
//
#include <hip/hip_runtime.h>
#include <math.h>

// Problem: x (8, 4096, 1024) fp32, softmax-like over axis 1 (stride 1024).
// Groups: g = b*1024 + c, 8192 groups of 4096 elements.

static constexpr int Bdim = 8;
static constexpr int Jdim = 4096;
static constexpr int Cdim = 1024;
static constexpr int JCHUNK = 64;               // rows per block chunk
static constexpr int NJC = Jdim / JCHUNK;       // 64 chunks along j
static constexpr int NG = Bdim * Cdim;          // 8192 groups
static constexpr int PSIZE = Bdim * NJC * Cdim; // 524288 partials

// ws layout (float offsets)
static constexpr int SC_OFF   = 0;              // [0]=amax_sub, [1]=max_s, [2]=min_s
static constexpr int GMAX_OFF = 16;             // 8192 group maxima of xq
static constexpr int S_OFF    = GMAX_OFF + NG;  // 8192 group sums of e_q
static constexpr int A_OFF    = S_OFF + NG;     // pmax in pass1, reused as psum in pass2
static constexpr int B_OFF    = A_OFF + PSIZE;  // pmin in pass1
// total floats: B_OFF + PSIZE = 1,064,976  (~4.1 MB) — well under typical ws_size

__device__ __forceinline__ float fq8(float x, float sinv, float s) {
    // clip(round(x/s), -128, 127) * s   (rintf = round-half-even, matches jnp.round)
    float q = rintf(x * sinv);
    q = fminf(fmaxf(q, -128.0f), 127.0f);
    return q * s;
}

// e_q = fq_auto(exp(fq_auto(clip(xq - gmax, -12, 0), q16)), q16)
// scale_e = 1/32767 exactly: the group-max element has sub==0 -> exp==1, and all e<=1.
__device__ __forceinline__ float eq_val(float xv, float sinv, float s, float gmax,
                                        float ssub_inv, float ssub) {
    float xq  = fq8(xv, sinv, s);
    float sub = fminf(fmaxf(xq - gmax, -12.0f), 0.0f);
    float q   = rintf(sub * ssub_inv);
    q = fminf(fmaxf(q, -32768.0f), 32767.0f);
    float e = __expf(q * ssub);
    return rintf(e * 32767.0f) * (1.0f / 32767.0f);
}

__global__ void k_init(float* __restrict__ ws) {
    ws[SC_OFF + 0] = 0.0f;                        // amax_sub (>=0, atomicMax)
    ws[SC_OFF + 1] = 0.0f;                        // max_s    (>0, atomicMax)
    ws[SC_OFF + 2] = __int_as_float(0x7f800000);  // min_s = +inf (atomicMin)
}

// Pass 1: per-(group, jchunk) partial max/min of xq.
__global__ __launch_bounds__(256) void k_pass1(const float* __restrict__ x,
                                               const float* __restrict__ scale,
                                               float* __restrict__ ws) {
    const int b  = blockIdx.x / NJC;
    const int jc = blockIdx.x % NJC;
    const int c0 = threadIdx.x * 4;
    const float s = scale[0];
    const float sinv = 1.0f / s;
    const float* px = x + ((size_t)(b * Jdim + jc * JCHUNK)) * Cdim + c0;

    float4 vmax = make_float4(-INFINITY, -INFINITY, -INFINITY, -INFINITY);
    float4 vmin = make_float4( INFINITY,  INFINITY,  INFINITY,  INFINITY);
    for (int r = 0; r < JCHUNK; ++r) {
        const float4 v = *reinterpret_cast<const float4*>(px + (size_t)r * Cdim);
        float q0 = fq8(v.x, sinv, s), q1 = fq8(v.y, sinv, s);
        float q2 = fq8(v.z, sinv, s), q3 = fq8(v.w, sinv, s);
        vmax.x = fmaxf(vmax.x, q0); vmin.x = fminf(vmin.x, q0);
        vmax.y = fmaxf(vmax.y, q1); vmin.y = fminf(vmin.y, q1);
        vmax.z = fmaxf(vmax.z, q2); vmin.z = fminf(vmin.z, q2);
        vmax.w = fmaxf(vmax.w, q3); vmin.w = fminf(vmin.w, q3);
    }
    const size_t pidx = ((size_t)(b * NJC + jc)) * Cdim + c0;
    *reinterpret_cast<float4*>(ws + A_OFF + pidx) = vmax;
    *reinterpret_cast<float4*>(ws + B_OFF + pidx) = vmin;
}

// Reduce 1: gmax per group; amax_sub = max_g min(12, gmax-gmin) (exact: q-grid values)
__global__ __launch_bounds__(256) void k_reduce1(float* __restrict__ ws) {
    const int g = blockIdx.x * 256 + threadIdx.x;   // 0..8191
    const int b = g / Cdim, c = g % Cdim;
    float gmax = -INFINITY, gmin = INFINITY;
    for (int jc = 0; jc < NJC; ++jc) {
        const size_t idx = ((size_t)(b * NJC + jc)) * Cdim + c;
        gmax = fmaxf(gmax, ws[A_OFF + idx]);
        gmin = fminf(gmin, ws[B_OFF + idx]);
    }
    ws[GMAX_OFF + g] = gmax;
    float d = fminf(12.0f, gmax - gmin);

    __shared__ float red[256];
    red[threadIdx.x] = d;
    __syncthreads();
    for (int off = 128; off; off >>= 1) {
        if (threadIdx.x < off) red[threadIdx.x] = fmaxf(red[threadIdx.x], red[threadIdx.x + off]);
        __syncthreads();
    }
    if (threadIdx.x == 0)
        atomicMax(reinterpret_cast<unsigned int*>(ws + SC_OFF + 0), __float_as_uint(red[0]));
}

// Pass 2: per-(group, jchunk) partial sums of e_q (fixed order -> deterministic).
__global__ __launch_bounds__(256) void k_pass2(const float* __restrict__ x,
                                               const float* __restrict__ scale,
                                               float* __restrict__ ws) {
    const int b  = blockIdx.x / NJC;
    const int jc = blockIdx.x % NJC;
    const int c0 = threadIdx.x * 4;
    const float s = scale[0];
    const float sinv = 1.0f / s;
    const float amax = fmaxf(ws[SC_OFF + 0], 1e-9f);
    const float ssub = amax / 32767.0f;
    const float ssub_inv = 1.0f / ssub;
    const float4 gm = *reinterpret_cast<const float4*>(ws + GMAX_OFF + b * Cdim + c0);
    const float* px = x + ((size_t)(b * Jdim + jc * JCHUNK)) * Cdim + c0;

    float4 acc = make_float4(0.f, 0.f, 0.f, 0.f);
    for (int r = 0; r < JCHUNK; ++r) {
        const float4 v = *reinterpret_cast<const float4*>(px + (size_t)r * Cdim);
        acc.x += eq_val(v.x, sinv, s, gm.x, ssub_inv, ssub);
        acc.y += eq_val(v.y, sinv, s, gm.y, ssub_inv, ssub);
        acc.z += eq_val(v.z, sinv, s, gm.z, ssub_inv, ssub);
        acc.w += eq_val(v.w, sinv, s, gm.w, ssub_inv, ssub);
    }
    const size_t pidx = ((size_t)(b * NJC + jc)) * Cdim + c0;
    *reinterpret_cast<float4*>(ws + A_OFF + pidx) = acc;   // reuse bufA (pmax consumed)
}

// Reduce 2: s per group (fixed order), global max_s / min_s.
__global__ __launch_bounds__(256) void k_reduce2(float* __restrict__ ws) {
    const int g = blockIdx.x * 256 + threadIdx.x;
    const int b = g / Cdim, c = g % Cdim;
    float ssum = 0.0f;
    for (int jc = 0; jc < NJC; ++jc)
        ssum += ws[A_OFF + ((size_t)(b * NJC + jc)) * Cdim + c];
    ws[S_OFF + g] = ssum;

    __shared__ float rmx[256], rmn[256];
    rmx[threadIdx.x] = ssum; rmn[threadIdx.x] = ssum;
    __syncthreads();
    for (int off = 128; off; off >>= 1) {
        if (threadIdx.x < off) {
            rmx[threadIdx.x] = fmaxf(rmx[threadIdx.x], rmx[threadIdx.x + off]);
            rmn[threadIdx.x] = fminf(rmn[threadIdx.x], rmn[threadIdx.x + off]);
        }
        __syncthreads();
    }
    if (threadIdx.x == 0) {
        atomicMax(reinterpret_cast<unsigned int*>(ws + SC_OFF + 1), __float_as_uint(rmx[0]));
        atomicMin(reinterpret_cast<unsigned int*>(ws + SC_OFF + 2), __float_as_uint(rmn[0]));
    }
}

// Pass 3: out = fq_auto(e_q * r_q, q8). All scales derived from 3 scalars (fq monotone).
__global__ __launch_bounds__(256) void k_pass3(const float* __restrict__ x,
                                               const float* __restrict__ scale,
                                               const float* __restrict__ ws,
                                               float* __restrict__ out) {
    const int b  = blockIdx.x / NJC;
    const int jc = blockIdx.x % NJC;
    const int c0 = threadIdx.x * 4;
    const float s = scale[0];
    const float sinv = 1.0f / s;

    const float amax = fmaxf(ws[SC_OFF + 0], 1e-9f);
    const float ssub = amax / 32767.0f;
    const float ssub_inv = 1.0f / ssub;

    const float max_s = ws[SC_OFF + 1];
    const float min_s = ws[SC_OFF + 2];
    const float scale_s = fmaxf(max_s, 1e-9f) / 32767.0f;
    const float ss_inv = 1.0f / scale_s;
    // min s_q = fq(min s) by monotonicity; max r = 1/min s_q; max r_q = fq(max r)
    float qmin = fminf(fmaxf(rintf(min_s * ss_inv), -32768.0f), 32767.0f);
    const float minsq = qmin * scale_s;
    const float maxr  = 1.0f / minsq;
    const float scale_r = fmaxf(maxr, 1e-9f) / 32767.0f;
    const float sr_inv  = 1.0f / scale_r;
    float qmr = fminf(fmaxf(rintf(maxr * sr_inv), -32768.0f), 32767.0f);
    const float maxrq = qmr * scale_r;                  // == maxr
    const float scale_out = fmaxf(maxrq, 1e-9f) / 127.0f;
    const float so_inv = 1.0f / scale_out;

    const float4 gm = *reinterpret_cast<const float4*>(ws + GMAX_OFF + b * Cdim + c0);
    const float4 s4 = *reinterpret_cast<const float4*>(ws + S_OFF    + b * Cdim + c0);

    // per-group r_q
    float4 rq;
    {
        float q0 = fminf(fmaxf(rintf(s4.x * ss_inv), -32768.0f), 32767.0f) * scale_s;
        float q1 = fminf(fmaxf(rintf(s4.y * ss_inv), -32768.0f), 32767.0f) * scale_s;
        float q2 = fminf(fmaxf(rintf(s4.z * ss_inv), -32768.0f), 32767.0f) * scale_s;
        float q3 = fminf(fmaxf(rintf(s4.w * ss_inv), -32768.0f), 32767.0f) * scale_s;
        float r0 = 1.0f / q0, r1 = 1.0f / q1, r2 = 1.0f / q2, r3 = 1.0f / q3;
        rq.x = fminf(fmaxf(rintf(r0 * sr_inv), -32768.0f), 32767.0f) * scale_r;
        rq.y = fminf(fmaxf(rintf(r1 * sr_inv), -32768.0f), 32767.0f) * scale_r;
        rq.z = fminf(fmaxf(rintf(r2 * sr_inv), -32768.0f), 32767.0f) * scale_r;
        rq.w = fminf(fmaxf(rintf(r3 * sr_inv), -32768.0f), 32767.0f) * scale_r;
    }

    const size_t base = ((size_t)(b * Jdim + jc * JCHUNK)) * Cdim + c0;
    const float* px = x + base;
    float* po = out + base;
    for (int r = 0; r < JCHUNK; ++r) {
        const float4 v = *reinterpret_cast<const float4*>(px + (size_t)r * Cdim);
        float4 o;
        {
            float e0 = eq_val(v.x, sinv, s, gm.x, ssub_inv, ssub) * rq.x;
            float e1 = eq_val(v.y, sinv, s, gm.y, ssub_inv, ssub) * rq.y;
            float e2 = eq_val(v.z, sinv, s, gm.z, ssub_inv, ssub) * rq.z;
            float e3 = eq_val(v.w, sinv, s, gm.w, ssub_inv, ssub) * rq.w;
            o.x = fminf(fmaxf(rintf(e0 * so_inv), -128.0f), 127.0f) * scale_out;
            o.y = fminf(fmaxf(rintf(e1 * so_inv), -128.0f), 127.0f) * scale_out;
            o.z = fminf(fmaxf(rintf(e2 * so_inv), -128.0f), 127.0f) * scale_out;
            o.w = fminf(fmaxf(rintf(e3 * so_inv), -128.0f), 127.0f) * scale_out;
        }
        *reinterpret_cast<float4*>(po + (size_t)r * Cdim) = o;
    }
}

extern "C" void kernel_launch(void* const* d_in, const int* in_sizes, int n_in,
                              void* d_out, int out_size, void* d_ws, size_t ws_size,
                              hipStream_t stream) {
    const float* x     = (const float*)d_in[0];
    const float* scale = (const float*)d_in[1];
    float* out = (float*)d_out;
    float* ws  = (float*)d_ws;

    k_init<<<1, 1, 0, stream>>>(ws);
    k_pass1<<<Bdim * NJC, 256, 0, stream>>>(x, scale, ws);
    k_reduce1<<<NG / 256, 256, 0, stream>>>(ws);
    k_pass2<<<Bdim * NJC, 256, 0, stream>>>(x, scale, ws);
    k_reduce2<<<NG / 256, 256, 0, stream>>>(ws);
    k_pass3<<<Bdim * NJC, 256, 0, stream>>>(x, scale, ws, out);
}